// Round 5
// baseline (449.603 us; speedup 1.0000x reference)
//
#include <hip/hip_runtime.h>

// Problem constants
#define MDIM 8192
#define IDIM 1024
#define ODIM 1024
#define D1   9            // DEGREE+1
#define KDIM (IDIM * D1)  // 9216, k = d*1024 + i ordering

typedef _Float16 half8   __attribute__((ext_vector_type(8)));
typedef float    float4v __attribute__((ext_vector_type(4)));

#define BSCALE 256.0f     // pre-scale B into f16-normal range (exact pow2)
#define INV_BSCALE (1.0f / 256.0f)
#define USCALE 5.123105625617661f    // sqrt(17) + 1
#define H0C 0.7511255444649425f     // pi^-1/4
#define SQRT2 1.4142135623730951f   // h1 = sqrt2 * u * h0

__device__ __forceinline__ half8 splat8(float f) {
    _Float16 h = (_Float16)f;
    return half8{h, h, h, h, h, h, h, h};
}

__constant__ float c1a[D1] = {0.f, 0.f, 1.0f, 0.8164965809277260f, 0.7071067811865476f,
                              0.6324555320336759f, 0.5773502691896258f, 0.5345224838248488f, 0.5f};
__constant__ float c2a[D1] = {0.f, 0.f, 0.7071067811865476f, 0.8164965809277260f, 0.8660254037844386f,
                              0.8944271909999159f, 0.9128709291752769f, 0.9258200997725514f, 0.9354143466934853f};

// ---------------------------------------------------------------------------
// hermite9 (fp32) — naive fallback only.
// ---------------------------------------------------------------------------
__device__ __forceinline__ void hermite9(float xv, float h[D1]) {
    float ax = fabsf(xv);
    float t  = __expf(-2.0f * ax);
    float th = (1.0f - t) / (1.0f + t);
    th = copysignf(th, xv);
    float u = th * USCALE;
    float g = __expf(-0.5f * u * u);
    h[0] = H0C * g;
    h[1] = SQRT2 * H0C * u * g;
#pragma unroll
    for (int d = 2; d < D1; ++d) h[d] = c1a[d] * u * h[d - 1] - c2a[d] * h[d - 2];
}

// ---------------------------------------------------------------------------
// prep_all: one launch, two bodies (wave-uniform split on blockIdx).
//  blocks [0,1024):      prep_b — LDS-transpose coeffs fp32 [I][O][9] ->
//                        Bt f16 [O][K] * 256, coalesced both phases.
//  blocks [1024, 5120):  prep_u — x -> u = USCALE*tanh(x), h0 = pi^-1/4*gauss.
// ---------------------------------------------------------------------------
__global__ __launch_bounds__(256) void prep_all(const float* __restrict__ C,
                                                _Float16* __restrict__ Bt,
                                                const float* __restrict__ x,
                                                _Float16* __restrict__ U,
                                                _Float16* __restrict__ H0) {
    if (blockIdx.x < 1024) {
        __shared__ float lds[288 * 33];
        const int t  = threadIdx.x;
        const int ti = blockIdx.x & 31;
        const int to = blockIdx.x >> 5;
        const float* base = C + (size_t)ti * 32 * 9216 + (size_t)to * 32 * 9;
#pragma unroll
        for (int j = 0; j < 36; ++j) {
            int f   = t + 256 * j;
            int row = f / 288;
            int col = f - row * 288;
            lds[col * 33 + row] = base[(size_t)row * 9216 + col];
        }
        __syncthreads();
        _Float16* bb = Bt + (size_t)to * 32 * KDIM + ti * 32;
#pragma unroll
        for (int j = 0; j < 36; ++j) {
            int e   = t + 256 * j;
            int i   = e & 31;
            int odp = e >> 5;
            int ol  = odp / 9;
            int d   = odp - ol * 9;
            bb[(size_t)ol * KDIM + d * IDIM + i] = (_Float16)(lds[odp * 33 + i] * BSCALE);
        }
    } else {
        size_t t = (size_t)(blockIdx.x - 1024) * 256 + threadIdx.x;
        const float4* xp = (const float4*)(x + t * 8);
        float4 a0 = xp[0], a1 = xp[1];
        float xv[8] = {a0.x, a0.y, a0.z, a0.w, a1.x, a1.y, a1.z, a1.w};
        half8 uu, hh;
#pragma unroll
        for (int e = 0; e < 8; ++e) {
            float v  = xv[e];
            float t2 = __expf(-2.0f * fabsf(v));
            float th = (1.0f - t2) * __builtin_amdgcn_rcpf(1.0f + t2);
            float u  = copysignf(th, v) * USCALE;
            float g  = __expf(-0.5f * u * u);
            uu[e] = (_Float16)u;
            hh[e] = (_Float16)(H0C * g);
        }
        *(half8*)(U  + t * 8) = uu;
        *(half8*)(H0 + t * 8) = hh;
    }
}

// ---------------------------------------------------------------------------
// gemm_reg: ZERO barriers, ZERO LDS. A-operands generated in registers via
// the pk-f16 Hermite recurrence (validated R4); B fragments loaded directly
// global->VGPR (dwordx4, 16 fully-consumed 64B lines per instr), register
// double-buffered one step ahead so the compiler pipelines with vmcnt(N).
// Each wave runs free — no in-phase drain. 128x128 block tile, 4 waves 2x2,
// 64x64 C per wave, 16x16x32 f16 MFMA. bn = blockflat%8 -> per-XCD L2-hot
// B panel (2.36 MB).
// ---------------------------------------------------------------------------
__global__ __launch_bounds__(256, 2) void gemm_reg(
    const _Float16* __restrict__ U,    // [8192][1024] f16
    const _Float16* __restrict__ H0,   // [8192][1024] f16
    const _Float16* __restrict__ Bt,   // [ODIM][KDIM], pre-scaled by 256
    float* __restrict__ out)           // [8192][ODIM]
{
    const int tid = threadIdx.x;
    const int w = tid >> 6;
    const int l = tid & 63;
    const int bn = blockIdx.x;    // n-tile 0..7 (= XCD id: flat%8)
    const int bm = blockIdx.y;    // m-tile 0..63

    const int q   = l >> 4;
    const int m16 = l & 15;
    const int wm  = w >> 1, wn = w & 1;

    // B row pointers: lane (q,m16), frag j -> row bn*128+wn*64+j*16+m16, +8q
    const _Float16* Brow[4];
#pragma unroll
    for (int j = 0; j < 4; ++j)
        Brow[j] = Bt + (size_t)(bn * 128 + wn * 64 + j * 16 + m16) * KDIM + 8 * q;

    // A state: lane (q,m16), m-frag i, k-half ko. Layout validated in R4.
    const size_t arow = ((size_t)(bm * 128 + wm * 64 + m16)) << 10;
    const _Float16* Ubase = U  + arow + 8 * q;
    const _Float16* Hbase = H0 + arow + 8 * q;

    half8 u2[4][2], hA[4][2], hB[4][2];
    half8 bbuf[2][4][2];
    float4v acc[4][4] = {};
    const half8 sq2v = splat8(SQRT2);

    auto loadUH = [&](int kb) {   // u2 and hA(=h0); hB derived at d==0
#pragma unroll
        for (int i = 0; i < 4; ++i)
#pragma unroll
            for (int ko = 0; ko < 2; ++ko) {
                size_t off = ((size_t)(i * 16) << 10) + kb + 32 * ko;
                u2[i][ko] = *(const half8*)(Ubase + off);
                hA[i][ko] = *(const half8*)(Hbase + off);
            }
    };

// One K-step. D, CUR, NXT are compile-time (unrolled). Loads for the NEXT
// step issue first (vmcnt prefetch), then per m-frag: recurrence (pk-f16
// VALU) fused with the 8 MFMAs of that frag.
#define HSTEP(D, CUR, NXT, HN, NK)                                                        \
    {                                                                                     \
        if (HN) {                                                                         \
            _Pragma("unroll")                                                             \
            for (int j = 0; j < 4; ++j) {                                                 \
                bbuf[NXT][j][0] = *(const half8*)(Brow[j] + (NK));                        \
                bbuf[NXT][j][1] = *(const half8*)(Brow[j] + (NK) + 32);                   \
            }                                                                             \
        }                                                                                 \
        _Pragma("unroll")                                                                 \
        for (int i = 0; i < 4; ++i) {                                                     \
            half8 af0, af1;                                                               \
            if ((D) == 0) {                                                               \
                hB[i][0] = sq2v * u2[i][0] * hA[i][0];                                    \
                hB[i][1] = sq2v * u2[i][1] * hA[i][1];                                    \
                af0 = hA[i][0]; af1 = hA[i][1];                                           \
            } else if ((D) == 1) {                                                        \
                af0 = hB[i][0]; af1 = hB[i][1];                                           \
            } else if ((D) < 8) {                                                         \
                const half8 c1v = splat8(c1a[(D)]);                                       \
                const half8 c2v = splat8(c2a[(D)]);                                       \
                af0 = c1v * (u2[i][0] * hB[i][0]) - c2v * hA[i][0];                       \
                af1 = c1v * (u2[i][1] * hB[i][1]) - c2v * hA[i][1];                       \
                hA[i][0] = hB[i][0]; hB[i][0] = af0;                                      \
                hA[i][1] = hB[i][1]; hB[i][1] = af1;                                      \
            } else {                                                                      \
                const half8 c1v = splat8(c1a[8]);                                         \
                const half8 c2v = splat8(c2a[8]);                                         \
                af0 = c1v * (u2[i][0] * hB[i][0]) - c2v * hA[i][0];                       \
                af1 = c1v * (u2[i][1] * hB[i][1]) - c2v * hA[i][1];                       \
            }                                                                             \
            _Pragma("unroll")                                                             \
            for (int j = 0; j < 4; ++j) {                                                 \
                acc[i][j] = __builtin_amdgcn_mfma_f32_16x16x32_f16(af0, bbuf[CUR][j][0],  \
                                                                   acc[i][j], 0, 0, 0);   \
                acc[i][j] = __builtin_amdgcn_mfma_f32_16x16x32_f16(af1, bbuf[CUR][j][1],  \
                                                                   acc[i][j], 0, 0, 0);   \
            }                                                                             \
        }                                                                                 \
    }

    // ---- prologue: A state + B frags for step (ib=0, d=0)
    loadUH(0);
#pragma unroll
    for (int j = 0; j < 4; ++j) {
        bbuf[0][j][0] = *(const half8*)(Brow[j]);
        bbuf[0][j][1] = *(const half8*)(Brow[j] + 32);
    }

    // ---- K loop: ib unrolled by 2 so buffer parity is compile-time.
    for (int ib2 = 0; ib2 < 16; ib2 += 2) {
        const int kb0 = ib2 * 64;
        const int kb1 = kb0 + 64;
        // even ib: step parity = d&1
#pragma unroll
        for (int d = 0; d < 9; ++d) {
            if (d < 8) {
                const int nk = (d + 1) * IDIM + kb0;
                if (d & 1) { HSTEP(d, 1, 0, true, nk) } else { HSTEP(d, 0, 1, true, nk) }
            } else {
                HSTEP(8, 0, 1, true, kb1)
                loadUH(kb1);          // next i-block's u/h0 (old state consumed)
            }
        }
        // odd ib: step parity = (d+1)&1
#pragma unroll
        for (int d = 0; d < 9; ++d) {
            if (d < 8) {
                const int nk = (d + 1) * IDIM + kb1;
                if (d & 1) { HSTEP(d, 0, 1, true, nk) } else { HSTEP(d, 1, 0, true, nk) }
            } else {
                const bool hn = (ib2 < 14);
                HSTEP(8, 1, 0, hn, kb1 + 64)
                if (hn) loadUH(kb1 + 64);
            }
        }
    }
#undef HSTEP

    // epilogue: D row = quad*4 + reg, col = lane&15 (m89-verified layout)
#pragma unroll
    for (int i = 0; i < 4; ++i) {
        int row = bm * 128 + wm * 64 + i * 16 + q * 4;
#pragma unroll
        for (int j = 0; j < 4; ++j) {
            int col = bn * 128 + wn * 64 + j * 16 + m16;
            float* op = out + (size_t)row * ODIM + col;
#pragma unroll
            for (int r2 = 0; r2 < 4; ++r2)
                op[(size_t)r2 * ODIM] = acc[i][j][r2] * INV_BSCALE;
        }
    }
}

// ---------------------------------------------------------------------------
// naive fallback (only if workspace can't hold Bt + U + H0, 52.4 MB)
// ---------------------------------------------------------------------------
__global__ void naive_kernel(const float* __restrict__ x, const float* __restrict__ C,
                             float* __restrict__ out) {
    __shared__ float hb[IDIM * D1];
    int b = blockIdx.x;
    int tid = threadIdx.x;
    for (int i = tid; i < IDIM; i += 256) {
        float h[D1];
        hermite9(x[(size_t)b * IDIM + i], h);
#pragma unroll
        for (int d = 0; d < D1; ++d) hb[i * D1 + d] = h[d];
    }
    __syncthreads();
    for (int o = tid; o < ODIM; o += 256) {
        float acc = 0.f;
        for (int i = 0; i < IDIM; ++i) {
            const float* cp = C + ((size_t)i * ODIM + o) * D1;
            const float* hp = hb + i * D1;
#pragma unroll
            for (int d = 0; d < D1; ++d) acc += hp[d] * cp[d];
        }
        out[(size_t)b * ODIM + o] = acc;
    }
}

// ---------------------------------------------------------------------------
extern "C" void kernel_launch(void* const* d_in, const int* in_sizes, int n_in,
                              void* d_out, int out_size, void* d_ws, size_t ws_size,
                              hipStream_t stream) {
    const float* x      = (const float*)d_in[0];   // [8192][1024]
    const float* coeffs = (const float*)d_in[1];   // [1024][1024][9]
    float* out = (float*)d_out;                    // [8192][1024]

    const size_t bt_bytes = (size_t)ODIM * KDIM * sizeof(_Float16);   // 18.9 MB
    const size_t u_bytes  = (size_t)MDIM * IDIM * sizeof(_Float16);   // 16.8 MB

    if (ws_size >= bt_bytes + 2 * u_bytes) {
        _Float16* Bt = (_Float16*)d_ws;
        _Float16* Uv = (_Float16*)((char*)d_ws + bt_bytes);
        _Float16* H0 = (_Float16*)((char*)d_ws + bt_bytes + u_bytes);
        hipLaunchKernelGGL(prep_all, dim3(1024 + (MDIM * IDIM) / 2048), dim3(256), 0, stream,
                           coeffs, Bt, x, Uv, H0);
        hipLaunchKernelGGL(gemm_reg, dim3(8, 64), dim3(256), 0, stream, Uv, H0, Bt, out);
    } else {
        hipLaunchKernelGGL(naive_kernel, dim3(MDIM), dim3(256), 0, stream, x, coeffs, out);
    }
}

// Round 6
// 331.357 us; speedup vs baseline: 1.3569x; 1.3569x over previous
//
#include <hip/hip_runtime.h>

// Problem constants
#define MDIM 8192
#define IDIM 1024
#define ODIM 1024
#define D1   9            // DEGREE+1
#define KDIM (IDIM * D1)  // 9216, k = d*1024 + i ordering
#define KHALF (KDIM / 2)  // 4608 = 72 x 64-k steps per K-split half

typedef _Float16 half8   __attribute__((ext_vector_type(8)));
typedef float    float4v __attribute__((ext_vector_type(4)));

#define BSCALE 256.0f     // pre-scale B into f16-normal range (exact pow2)
#define INV_BSCALE (1.0f / 256.0f)
#define USCALE 5.123105625617661f    // sqrt(17) + 1
#define H0C 0.7511255444649425f     // pi^-1/4
#define SQRT2 1.4142135623730951f

__constant__ float c1a[D1] = {0.f, 0.f, 1.0f, 0.8164965809277260f, 0.7071067811865476f,
                              0.6324555320336759f, 0.5773502691896258f, 0.5345224838248488f, 0.5f};
__constant__ float c2a[D1] = {0.f, 0.f, 0.7071067811865476f, 0.8164965809277260f, 0.8660254037844386f,
                              0.8944271909999159f, 0.9128709291752769f, 0.9258200997725514f, 0.9354143466934853f};

// ---------------------------------------------------------------------------
// hermite9 (fp32)
// ---------------------------------------------------------------------------
__device__ __forceinline__ void hermite9(float xv, float h[D1]) {
    float ax = fabsf(xv);
    float t  = __expf(-2.0f * ax);
    float th = (1.0f - t) * __builtin_amdgcn_rcpf(1.0f + t);
    th = copysignf(th, xv);
    float u = th * USCALE;
    float g = __expf(-0.5f * u * u);
    h[0] = H0C * g;
    h[1] = SQRT2 * H0C * u * g;
#pragma unroll
    for (int d = 2; d < D1; ++d) h[d] = c1a[d] * u * h[d - 1] - c2a[d] * h[d - 2];
}

// ---------------------------------------------------------------------------
// prep_all: one launch, two bodies (wave-uniform split on blockIdx).
//  blocks [0,1024):       prep_b — LDS-transpose coeffs fp32 [I][O][9] ->
//                         Bt f16 [O][K] * 256, coalesced both phases.
//  blocks [1024, 5120):   prep_h — x -> FULL Hermite basis H f16 [8192][KDIM],
//                         H[r][d*1024+i] = h_d(u(x[r][i])). 2 rows/block,
//                         128 thr/row, 8 i/thr, half8 (16B) coalesced stores.
//                         Done ONCE here (vs 8x redundantly in-GEMM).
// ---------------------------------------------------------------------------
__global__ __launch_bounds__(256) void prep_all(const float* __restrict__ C,
                                                _Float16* __restrict__ Bt,
                                                const float* __restrict__ x,
                                                _Float16* __restrict__ H) {
    if (blockIdx.x < 1024) {
        __shared__ float lds[288 * 33];
        const int t  = threadIdx.x;
        const int ti = blockIdx.x & 31;
        const int to = blockIdx.x >> 5;
        const float* base = C + (size_t)ti * 32 * 9216 + (size_t)to * 32 * 9;
#pragma unroll
        for (int j = 0; j < 36; ++j) {
            int f   = t + 256 * j;
            int row = f / 288;
            int col = f - row * 288;
            lds[col * 33 + row] = base[(size_t)row * 9216 + col];
        }
        __syncthreads();
        _Float16* bb = Bt + (size_t)to * 32 * KDIM + ti * 32;
#pragma unroll
        for (int j = 0; j < 36; ++j) {
            int e   = t + 256 * j;
            int i   = e & 31;
            int odp = e >> 5;
            int ol  = odp / 9;
            int d   = odp - ol * 9;
            bb[(size_t)ol * KDIM + d * IDIM + i] = (_Float16)(lds[odp * 33 + i] * BSCALE);
        }
    } else {
        int t  = (blockIdx.x - 1024) * 256 + threadIdx.x;
        int r  = t >> 7;                 // row 0..8191
        int ig = (t & 127) << 3;         // i0
        const float* xp = x + (((size_t)r) << 10) + ig;
        float4 a0 = *(const float4*)xp;
        float4 a1 = *(const float4*)(xp + 4);
        float xv[8] = {a0.x, a0.y, a0.z, a0.w, a1.x, a1.y, a1.z, a1.w};
        float h[8][D1];
#pragma unroll
        for (int e = 0; e < 8; ++e) hermite9(xv[e], h[e]);
        _Float16* hp = H + (size_t)r * KDIM + ig;
#pragma unroll
        for (int d = 0; d < D1; ++d) {
            half8 v;
#pragma unroll
            for (int e = 0; e < 8; ++e) v[e] = (_Float16)h[e][d];
            *(half8*)(hp + (size_t)d * IDIM) = v;
        }
    }
}

// ---------------------------------------------------------------------------
// gemm_hf: C[m][n] += A[m][k] * Bt[n][k] over one K-half, f16 MFMA 16x16x32.
// Exactly the R1 (176 us, 40% MfmaUtil) structure — A & B staged via
// global_load_lds dwordx4, XOR k-group swizzle (0 bank conflicts), 128x128
// tile, 4 waves 2x2 — but split-K x2 (blockIdx.z): grid = 1024 blocks ->
// 4 resident blocks/CU (4 independent barrier groups interleave to fill the
// per-block DMA-drain stall that capped R1 at 2 blocks/CU). fp32 atomicAdd
// epilogue into pre-zeroed out.
// ---------------------------------------------------------------------------
__global__ __launch_bounds__(256, 4) void gemm_hf(
    const _Float16* __restrict__ A,    // H [8192][KDIM]
    const _Float16* __restrict__ Bt,   // [ODIM][KDIM]
    float* __restrict__ out)           // [8192][ODIM], pre-zeroed
{
    const int tid = threadIdx.x;
    const int w = tid >> 6;
    const int l = tid & 63;
    const int bn = blockIdx.x;    // n-tile 0..7 (flat%8 = XCD -> L2-hot B panel)
    const int bm = blockIdx.y;    // m-tile 0..63
    const int kb0 = blockIdx.z * KHALF;   // K-split half

    __shared__ _Float16 As[128 * 64];
    __shared__ _Float16 Bs[128 * 64];

    // staging: lane l, rep r loads 16B into (row, l&7); data kgrp = (l&7)^(l>>3)
    const int lrow8 = l >> 3;
    const int kgrp  = (l & 7) ^ lrow8;
    const _Float16* Ag = A  + ((size_t)(bm * 128 + w * 8 + lrow8) * KDIM + kb0 + kgrp * 8);
    const _Float16* Bg = Bt + ((size_t)(bn * 128 + w * 8 + lrow8) * KDIM + kb0 + kgrp * 8);

    // compute-side fragment indices
    const int q   = l >> 4;
    const int m16 = l & 15;
    const int s3  = m16 & 7;
    const int wm  = w >> 1, wn = w & 1;

    float4v acc[4][4] = {};

    for (int k0 = 0; k0 < KHALF; k0 += 64) {
#pragma unroll
        for (int r = 0; r < 4; ++r) {
            __builtin_amdgcn_global_load_lds(
                (const __attribute__((address_space(1))) void*)(Ag + (size_t)(r * 32) * KDIM + k0),
                (__attribute__((address_space(3))) void*)((char*)As + (r * 4 + w) * 1024),
                16, 0, 0);
            __builtin_amdgcn_global_load_lds(
                (const __attribute__((address_space(1))) void*)(Bg + (size_t)(r * 32) * KDIM + k0),
                (__attribute__((address_space(3))) void*)((char*)Bs + (r * 4 + w) * 1024),
                16, 0, 0);
        }
        __syncthreads();   // drains DMA, publishes tiles

#pragma unroll
        for (int ko = 0; ko < 2; ++ko) {
            const int slot = (q + 4 * ko) ^ s3;
            half8 af[4], bf[4];
#pragma unroll
            for (int i = 0; i < 4; ++i) {
                af[i] = *(const half8*)&As[(wm * 64 + i * 16 + m16) * 64 + slot * 8];
                bf[i] = *(const half8*)&Bs[(wn * 64 + i * 16 + m16) * 64 + slot * 8];
            }
#pragma unroll
            for (int i = 0; i < 4; ++i)
#pragma unroll
                for (int j = 0; j < 4; ++j)
                    acc[i][j] = __builtin_amdgcn_mfma_f32_16x16x32_f16(af[i], bf[j], acc[i][j], 0, 0, 0);
        }
        __syncthreads();   // tiles consumed, safe to overwrite
    }

    // epilogue: D row = quad*4 + reg, col = lane&15 (m89 layout); K-split halves
    // accumulate via device-scope fp32 atomics into the zeroed output.
#pragma unroll
    for (int i = 0; i < 4; ++i) {
        int row = bm * 128 + wm * 64 + i * 16 + q * 4;
#pragma unroll
        for (int j = 0; j < 4; ++j) {
            int col = bn * 128 + wn * 64 + j * 16 + m16;
            float* op = out + (size_t)row * ODIM + col;
#pragma unroll
            for (int r2 = 0; r2 < 4; ++r2)
                atomicAdd(op + (size_t)r2 * ODIM, acc[i][j][r2] * INV_BSCALE);
        }
    }
}

// ---------------------------------------------------------------------------
// naive fallback (only if workspace can't hold Bt + H, 170 MB)
// ---------------------------------------------------------------------------
__global__ void naive_kernel(const float* __restrict__ x, const float* __restrict__ C,
                             float* __restrict__ out) {
    __shared__ float hb[IDIM * D1];
    int b = blockIdx.x;
    int tid = threadIdx.x;
    for (int i = tid; i < IDIM; i += 256) {
        float h[D1];
        hermite9(x[(size_t)b * IDIM + i], h);
#pragma unroll
        for (int d = 0; d < D1; ++d) hb[i * D1 + d] = h[d];
    }
    __syncthreads();
    for (int o = tid; o < ODIM; o += 256) {
        float acc = 0.f;
        for (int i = 0; i < IDIM; ++i) {
            const float* cp = C + ((size_t)i * ODIM + o) * D1;
            const float* hp = hb + i * D1;
#pragma unroll
            for (int d = 0; d < D1; ++d) acc += hp[d] * cp[d];
        }
        out[(size_t)b * ODIM + o] = acc;
    }
}

// ---------------------------------------------------------------------------
extern "C" void kernel_launch(void* const* d_in, const int* in_sizes, int n_in,
                              void* d_out, int out_size, void* d_ws, size_t ws_size,
                              hipStream_t stream) {
    const float* x      = (const float*)d_in[0];   // [8192][1024]
    const float* coeffs = (const float*)d_in[1];   // [1024][1024][9]
    float* out = (float*)d_out;                    // [8192][1024]

    const size_t bt_bytes = (size_t)ODIM * KDIM * sizeof(_Float16);   // 18.9 MB
    const size_t h_bytes  = (size_t)MDIM * KDIM * sizeof(_Float16);   // 151.0 MB

    if (ws_size >= bt_bytes + h_bytes) {
        _Float16* Bt = (_Float16*)d_ws;
        _Float16* H  = (_Float16*)((char*)d_ws + bt_bytes);
        hipMemsetAsync(out, 0, (size_t)out_size * sizeof(float), stream);
        hipLaunchKernelGGL(prep_all, dim3(1024 + (MDIM * IDIM) / 2048), dim3(256), 0, stream,
                           coeffs, Bt, x, H);
        hipLaunchKernelGGL(gemm_hf, dim3(8, 64, 2), dim3(256), 0, stream, H, Bt, out);
    } else {
        hipLaunchKernelGGL(naive_kernel, dim3(MDIM), dim3(256), 0, stream, x, coeffs, out);
    }
}

// Round 7
// 303.633 us; speedup vs baseline: 1.4807x; 1.0913x over previous
//
#include <hip/hip_runtime.h>

// Problem constants
#define MDIM 8192
#define IDIM 1024
#define ODIM 1024
#define D1   9            // DEGREE+1
#define KDIM (IDIM * D1)  // 9216, k = d*1024 + i ordering
#define NSTEP (KDIM / 64) // 144 k-steps

typedef _Float16 half8   __attribute__((ext_vector_type(8)));
typedef float    float4v __attribute__((ext_vector_type(4)));

#define BSCALE 256.0f     // pre-scale B into f16-normal range (exact pow2)
#define INV_BSCALE (1.0f / 256.0f)
#define USCALE 5.123105625617661f    // sqrt(17) + 1
#define H0C 0.7511255444649425f     // pi^-1/4
#define SQRT2 1.4142135623730951f

__constant__ float c1a[D1] = {0.f, 0.f, 1.0f, 0.8164965809277260f, 0.7071067811865476f,
                              0.6324555320336759f, 0.5773502691896258f, 0.5345224838248488f, 0.5f};
__constant__ float c2a[D1] = {0.f, 0.f, 0.7071067811865476f, 0.8164965809277260f, 0.8660254037844386f,
                              0.8944271909999159f, 0.9128709291752769f, 0.9258200997725514f, 0.9354143466934853f};

// ---------------------------------------------------------------------------
__device__ __forceinline__ void hermite9(float xv, float h[D1]) {
    float ax = fabsf(xv);
    float t  = __expf(-2.0f * ax);
    float th = (1.0f - t) * __builtin_amdgcn_rcpf(1.0f + t);
    th = copysignf(th, xv);
    float u = th * USCALE;
    float g = __expf(-0.5f * u * u);
    h[0] = H0C * g;
    h[1] = SQRT2 * H0C * u * g;
#pragma unroll
    for (int d = 2; d < D1; ++d) h[d] = c1a[d] * u * h[d - 1] - c2a[d] * h[d - 2];
}

// ---------------------------------------------------------------------------
// prep_all: one launch, two bodies (wave-uniform split on blockIdx).
//  blocks [0,1024):     prep_b — LDS-transpose coeffs fp32 [I][O][9] ->
//                       Bt f16 [O][K] * 256, coalesced both phases.
//  blocks [1024,5120):  prep_h — x -> full Hermite basis H f16 [8192][KDIM].
// ---------------------------------------------------------------------------
__global__ __launch_bounds__(256) void prep_all(const float* __restrict__ C,
                                                _Float16* __restrict__ Bt,
                                                const float* __restrict__ x,
                                                _Float16* __restrict__ H) {
    if (blockIdx.x < 1024) {
        __shared__ float lds[288 * 33];
        const int t  = threadIdx.x;
        const int ti = blockIdx.x & 31;
        const int to = blockIdx.x >> 5;
        const float* base = C + (size_t)ti * 32 * 9216 + (size_t)to * 32 * 9;
#pragma unroll
        for (int j = 0; j < 36; ++j) {
            int f   = t + 256 * j;
            int row = f / 288;
            int col = f - row * 288;
            lds[col * 33 + row] = base[(size_t)row * 9216 + col];
        }
        __syncthreads();
        _Float16* bb = Bt + (size_t)to * 32 * KDIM + ti * 32;
#pragma unroll
        for (int j = 0; j < 36; ++j) {
            int e   = t + 256 * j;
            int i   = e & 31;
            int odp = e >> 5;
            int ol  = odp / 9;
            int d   = odp - ol * 9;
            bb[(size_t)ol * KDIM + d * IDIM + i] = (_Float16)(lds[odp * 33 + i] * BSCALE);
        }
    } else {
        int t  = (blockIdx.x - 1024) * 256 + threadIdx.x;
        int r  = t >> 7;                 // row 0..8191
        int ig = (t & 127) << 3;         // i0
        const float* xp = x + (((size_t)r) << 10) + ig;
        float4 a0 = *(const float4*)xp;
        float4 a1 = *(const float4*)(xp + 4);
        float xv[8] = {a0.x, a0.y, a0.z, a0.w, a1.x, a1.y, a1.z, a1.w};
        float h[8][D1];
#pragma unroll
        for (int e = 0; e < 8; ++e) hermite9(xv[e], h[e]);
        _Float16* hp = H + (size_t)r * KDIM + ig;
#pragma unroll
        for (int d = 0; d < D1; ++d) {
            half8 v;
#pragma unroll
            for (int e = 0; e < 8; ++e) v[e] = (_Float16)h[e][d];
            *(half8*)(hp + (size_t)d * IDIM) = v;
        }
    }
}

// ---------------------------------------------------------------------------
// gemm_db: single-barrier ring double-buffer. Per step s: barrier (publishes
// buf[cur], DMA'd one full compute phase ago -> drain ~free; frees buf[nxt]);
// issue DMA(s+1) -> buf[nxt]; ds_read + 32 MFMA on buf[cur]. No second
// barrier — the R4-validated pattern, now with zero producer VALU (H is
// precomputed). 128x128 tile, 4 waves 2x2, 16x16x32 f16 MFMA, XOR-swizzled
// LDS (0 conflicts), LDS 64 KB -> 2 blocks/CU.
// ---------------------------------------------------------------------------
__global__ __launch_bounds__(256, 2) void gemm_db(
    const _Float16* __restrict__ A,    // H [8192][KDIM]
    const _Float16* __restrict__ Bt,   // [ODIM][KDIM]
    float* __restrict__ out)           // [8192][ODIM]
{
    const int tid = threadIdx.x;
    const int w = tid >> 6;
    const int l = tid & 63;
    const int bn = blockIdx.x;    // n-tile 0..7 (flat%8 = XCD -> L2-hot B panel)
    const int bm = blockIdx.y;    // m-tile 0..63

    __shared__ _Float16 As[2][128 * 64];
    __shared__ _Float16 Bs[2][128 * 64];

    // staging: lane l, rep r loads 16B into LDS row (r*4+w)*8 + l/8, byte col
    // (l&7)*16; stored data k-group = (l&7)^(l>>3)  (XOR swizzle)
    const int lrow8 = l >> 3;
    const int kgrp  = (l & 7) ^ lrow8;
    const _Float16* Ag = A  + ((size_t)(bm * 128 + w * 8 + lrow8) * KDIM + kgrp * 8);
    const _Float16* Bg = Bt + ((size_t)(bn * 128 + w * 8 + lrow8) * KDIM + kgrp * 8);

    // compute-side fragment indices
    const int q   = l >> 4;
    const int m16 = l & 15;
    const int s3  = m16 & 7;
    const int wm  = w >> 1, wn = w & 1;

    float4v acc[4][4] = {};

    auto stage = [&](int buf, int k0) {
#pragma unroll
        for (int r = 0; r < 4; ++r) {
            __builtin_amdgcn_global_load_lds(
                (const __attribute__((address_space(1))) void*)(Ag + (size_t)(r * 32) * KDIM + k0),
                (__attribute__((address_space(3))) void*)((char*)&As[buf][0] + (r * 4 + w) * 1024),
                16, 0, 0);
            __builtin_amdgcn_global_load_lds(
                (const __attribute__((address_space(1))) void*)(Bg + (size_t)(r * 32) * KDIM + k0),
                (__attribute__((address_space(3))) void*)((char*)&Bs[buf][0] + (r * 4 + w) * 1024),
                16, 0, 0);
        }
    };

    auto compute = [&](int buf) {
#pragma unroll
        for (int ko = 0; ko < 2; ++ko) {
            const int slot = (q + 4 * ko) ^ s3;
            half8 af[4], bf[4];
#pragma unroll
            for (int i = 0; i < 4; ++i) {
                af[i] = *(const half8*)&As[buf][(wm * 64 + i * 16 + m16) * 64 + slot * 8];
                bf[i] = *(const half8*)&Bs[buf][(wn * 64 + i * 16 + m16) * 64 + slot * 8];
            }
#pragma unroll
            for (int i = 0; i < 4; ++i)
#pragma unroll
                for (int j = 0; j < 4; ++j)
                    acc[i][j] = __builtin_amdgcn_mfma_f32_16x16x32_f16(af[i], bf[j], acc[i][j], 0, 0, 0);
        }
    };

    // prologue: DMA step 0 into buf 0
    stage(0, 0);

    // ring: unrolled by 2 so buffer index is compile-time
    for (int s2 = 0; s2 < NSTEP; s2 += 2) {
        __syncthreads();                       // buf0 ready; buf1 free
        stage(1, (s2 + 1) * 64);               // s2+1 <= 143 always valid
        compute(0);
        __syncthreads();                       // buf1 ready; buf0 free
        if (s2 + 2 < NSTEP) stage(0, (s2 + 2) * 64);
        compute(1);
    }

    // epilogue: D row = quad*4 + reg, col = lane&15 (m89-verified layout)
#pragma unroll
    for (int i = 0; i < 4; ++i) {
        int row = bm * 128 + wm * 64 + i * 16 + q * 4;
#pragma unroll
        for (int j = 0; j < 4; ++j) {
            int col = bn * 128 + wn * 64 + j * 16 + m16;
            float* op = out + (size_t)row * ODIM + col;
#pragma unroll
            for (int r2 = 0; r2 < 4; ++r2)
                op[(size_t)r2 * ODIM] = acc[i][j][r2] * INV_BSCALE;
        }
    }
}

// ---------------------------------------------------------------------------
// naive fallback (only if workspace can't hold Bt + H, 170 MB)
// ---------------------------------------------------------------------------
__global__ void naive_kernel(const float* __restrict__ x, const float* __restrict__ C,
                             float* __restrict__ out) {
    __shared__ float hb[IDIM * D1];
    int b = blockIdx.x;
    int tid = threadIdx.x;
    for (int i = tid; i < IDIM; i += 256) {
        float h[D1];
        hermite9(x[(size_t)b * IDIM + i], h);
#pragma unroll
        for (int d = 0; d < D1; ++d) hb[i * D1 + d] = h[d];
    }
    __syncthreads();
    for (int o = tid; o < ODIM; o += 256) {
        float acc = 0.f;
        for (int i = 0; i < IDIM; ++i) {
            const float* cp = C + ((size_t)i * ODIM + o) * D1;
            const float* hp = hb + i * D1;
#pragma unroll
            for (int d = 0; d < D1; ++d) acc += hp[d] * cp[d];
        }
        out[(size_t)b * ODIM + o] = acc;
    }
}

// ---------------------------------------------------------------------------
extern "C" void kernel_launch(void* const* d_in, const int* in_sizes, int n_in,
                              void* d_out, int out_size, void* d_ws, size_t ws_size,
                              hipStream_t stream) {
    const float* x      = (const float*)d_in[0];   // [8192][1024]
    const float* coeffs = (const float*)d_in[1];   // [1024][1024][9]
    float* out = (float*)d_out;                    // [8192][1024]

    const size_t bt_bytes = (size_t)ODIM * KDIM * sizeof(_Float16);   // 18.9 MB
    const size_t h_bytes  = (size_t)MDIM * KDIM * sizeof(_Float16);   // 151.0 MB

    if (ws_size >= bt_bytes + h_bytes) {
        _Float16* Bt = (_Float16*)d_ws;
        _Float16* H  = (_Float16*)((char*)d_ws + bt_bytes);
        hipLaunchKernelGGL(prep_all, dim3(1024 + (MDIM * IDIM) / 2048), dim3(256), 0, stream,
                           coeffs, Bt, x, H);
        hipLaunchKernelGGL(gemm_db, dim3(8, 64), dim3(256), 0, stream, H, Bt, out);
    } else {
        hipLaunchKernelGGL(naive_kernel, dim3(MDIM), dim3(256), 0, stream, x, coeffs, out);
    }
}